// Round 1
// baseline (2598.409 us; speedup 1.0000x reference)
//
#include <hip/hip_runtime.h>

#define B_SZ 4096
#define DM   768
#define DS   24576
#define TOPK 32
#define MAXC 256

// ---------------- Kernel 1: pre = A @ Wenc^T + b  (fp32, 64x64 tile) ----------------
__global__ __launch_bounds__(256) void k_gemm(const float* __restrict__ A,
                                              const float* __restrict__ W,
                                              const float* __restrict__ bias,
                                              float* __restrict__ pre) {
  __shared__ float As[16][64];
  __shared__ float Bs[16][64];
  const int n0 = blockIdx.x * 64;
  const int m0 = blockIdx.y * 64;
  const int tid = threadIdx.x;
  const int lrow = tid >> 2;   // 0..63 (tile row being loaded)
  const int lseg = tid & 3;    // 0..3  (float4 segment within 16-wide k)
  const int tx = tid & 15;     // output n sub-tile
  const int ty = tid >> 4;     // output m sub-tile

  float acc[4][4] = {};

  for (int kt = 0; kt < DM; kt += 16) {
    float4 a4 = *reinterpret_cast<const float4*>(A + (size_t)(m0 + lrow) * DM + kt + lseg * 4);
    float4 b4 = *reinterpret_cast<const float4*>(W + (size_t)(n0 + lrow) * DM + kt + lseg * 4);
    As[lseg * 4 + 0][lrow] = a4.x;
    As[lseg * 4 + 1][lrow] = a4.y;
    As[lseg * 4 + 2][lrow] = a4.z;
    As[lseg * 4 + 3][lrow] = a4.w;
    Bs[lseg * 4 + 0][lrow] = b4.x;
    Bs[lseg * 4 + 1][lrow] = b4.y;
    Bs[lseg * 4 + 2][lrow] = b4.z;
    Bs[lseg * 4 + 3][lrow] = b4.w;
    __syncthreads();
#pragma unroll
    for (int k = 0; k < 16; ++k) {
      float a[4], b[4];
      *reinterpret_cast<float4*>(a) = *reinterpret_cast<const float4*>(&As[k][ty * 4]);
      *reinterpret_cast<float4*>(b) = *reinterpret_cast<const float4*>(&Bs[k][tx * 4]);
#pragma unroll
      for (int i = 0; i < 4; ++i)
#pragma unroll
        for (int j = 0; j < 4; ++j) acc[i][j] = fmaf(a[i], b[j], acc[i][j]);
    }
    __syncthreads();
  }

  float4 bv = *reinterpret_cast<const float4*>(bias + n0 + tx * 4);
#pragma unroll
  for (int i = 0; i < 4; ++i) {
    float4 o;
    o.x = acc[i][0] + bv.x;
    o.y = acc[i][1] + bv.y;
    o.z = acc[i][2] + bv.z;
    o.w = acc[i][3] + bv.w;
    *reinterpret_cast<float4*>(pre + (size_t)(m0 + ty * 4 + i) * DS + n0 + tx * 4) = o;
  }
}

// ---------------- Kernel 2: per-row top-32 with fp64 boundary refinement ----------------
// Writes lists into out0 row b: floats [0..31] = vals, ints (bitcast) [32..63] = idxs.
__global__ __launch_bounds__(256) void k_topk(const float* __restrict__ pre,
                                              const float* __restrict__ A,
                                              const float* __restrict__ W,
                                              const float* __restrict__ bias,
                                              float* __restrict__ out0) {
  const int b = blockIdx.x;
  const int tid = threadIdx.x;
  __shared__ int hist[1024];
  __shared__ int chunk[64];
  __shared__ float sBinLo;
  __shared__ int cnt;
  __shared__ int cidx[MAXC];
  __shared__ double cval[MAXC];

  const float* row = pre + (size_t)b * DS;

  for (int i = tid; i < 1024; i += 256) hist[i] = 0;
  if (tid == 0) cnt = 0;
  __syncthreads();

  // histogram of fp32 pre-activations, bins of width 1/32 over [-16,16)
  for (int i = tid; i < DS; i += 256) {
    float v = row[i];
    int bin = (int)((v + 16.f) * 32.f);
    bin = bin < 0 ? 0 : (bin > 1023 ? 1023 : bin);
    atomicAdd(&hist[bin], 1);
  }
  __syncthreads();

  if (tid < 64) {
    int s = 0;
    for (int x = 0; x < 16; ++x) s += hist[tid * 16 + x];
    chunk[tid] = s;
  }
  __syncthreads();

  if (tid == 0) {
    int cum = 0, tb = 0;
    for (int c = 63; c >= 0; --c) {
      if (cum + chunk[c] >= TOPK) {
        int cc = cum;
        tb = c * 16;
        for (int x = 15; x >= 0; --x) {
          int bn = c * 16 + x;
          if (cc + hist[bn] >= TOPK) { tb = bn; break; }
          cc += hist[bn];
        }
        break;
      }
      cum += chunk[c];
    }
    int lb = tb - 1;  // one extra bin of margin (~0.031) for fp32-vs-fp64 swaps
    if (lb < 0) lb = 0;
    sBinLo = -16.f + (float)lb * (1.f / 32.f);
  }
  __syncthreads();

  const float binLo = sBinLo;
  for (int i = tid; i < DS; i += 256) {
    if (row[i] >= binLo) {
      int p = atomicAdd(&cnt, 1);
      if (p < MAXC) cidx[p] = i;
    }
  }
  __syncthreads();
  const int n = cnt < MAXC ? cnt : MAXC;

  // fp64 recompute of each candidate's dot product (one wave per candidate, round-robin)
  const float* Ar = A + (size_t)b * DM;
  const int w = tid >> 6, lane = tid & 63;
  for (int c = w; c < n; c += 4) {
    const float* Wr = W + (size_t)cidx[c] * DM;
    double s = 0.0;
    for (int d = lane; d < DM; d += 64) s += (double)Ar[d] * (double)Wr[d];
#pragma unroll
    for (int off = 32; off > 0; off >>= 1) s += __shfl_down(s, off);
    if (lane == 0) cval[c] = s + (double)bias[cidx[c]];
  }
  __syncthreads();

  // exact rank (value desc, tie -> lower index), matching jax.lax.top_k
  float* orow = out0 + (size_t)b * DM;
  if (tid < n) {
    double dv = cval[tid];
    int di = cidx[tid];
    int r = 0;
    for (int j = 0; j < n; ++j) {
      double o = cval[j];
      if (o > dv || (o == dv && cidx[j] < di)) ++r;
    }
    if (r < TOPK) {
      orow[r] = (float)dv;
      reinterpret_cast<int*>(orow)[TOPK + r] = di;
    }
  }
}

// ---------------- Kernel 3: scatter top-k values into zeroed latents ----------------
__global__ void k_scatter(const float* __restrict__ out0, float* __restrict__ latents) {
  int t = blockIdx.x * 256 + threadIdx.x;
  if (t < B_SZ * TOPK) {
    int b = t >> 5;
    int k = t & 31;
    const float* orow = out0 + (size_t)b * DM;
    int idx = reinterpret_cast<const int*>(orow)[TOPK + k];
    latents[(size_t)b * DS + idx] = orow[k];
  }
}

// ---------------- Kernel 4a: transpose W_dec [DM][DS] -> WdT [DS][DM] ----------------
__global__ void k_transpose(const float* __restrict__ in, float* __restrict__ out) {
  __shared__ float t[32][33];
  int sx = blockIdx.x * 32 + threadIdx.x;
  int d0 = blockIdx.y * 32;
#pragma unroll
  for (int j = 0; j < 32; j += 8)
    t[threadIdx.y + j][threadIdx.x] = in[(size_t)(d0 + threadIdx.y + j) * DS + sx];
  __syncthreads();
  int dx = d0 + threadIdx.x;
  int s0 = blockIdx.x * 32;
#pragma unroll
  for (int j = 0; j < 32; j += 8)
    out[(size_t)(s0 + threadIdx.y + j) * DM + dx] = t[threadIdx.x][threadIdx.y + j];
}

// ---------------- Kernel 4b: decode with transposed W_dec (coalesced) ----------------
__global__ __launch_bounds__(256) void k_decode(const float* __restrict__ WdT,
                                                float* __restrict__ out0) {
  const int b = blockIdx.x;
  __shared__ int sidx[TOPK];
  __shared__ float sval[TOPK];
  float* orow = out0 + (size_t)b * DM;
  if (threadIdx.x < TOPK) {
    sval[threadIdx.x] = orow[threadIdx.x];
    sidx[threadIdx.x] = reinterpret_cast<const int*>(orow)[TOPK + threadIdx.x];
  }
  __syncthreads();
  const int d = threadIdx.x;
  float a0 = 0.f, a1 = 0.f, a2 = 0.f;
#pragma unroll
  for (int k = 0; k < TOPK; ++k) {
    const float* wr = WdT + (size_t)sidx[k] * DM;
    float v = sval[k];
    a0 = fmaf(v, wr[d], a0);
    a1 = fmaf(v, wr[d + 256], a1);
    a2 = fmaf(v, wr[d + 512], a2);
  }
  orow[d] = a0;
  orow[d + 256] = a1;
  orow[d + 512] = a2;
}

// ---------------- Kernel 4b': decode fallback without transpose (strided) ----------------
__global__ __launch_bounds__(256) void k_decode_slow(const float* __restrict__ Wd,
                                                     float* __restrict__ out0) {
  const int b = blockIdx.x;
  __shared__ int sidx[TOPK];
  __shared__ float sval[TOPK];
  float* orow = out0 + (size_t)b * DM;
  if (threadIdx.x < TOPK) {
    sval[threadIdx.x] = orow[threadIdx.x];
    sidx[threadIdx.x] = reinterpret_cast<const int*>(orow)[TOPK + threadIdx.x];
  }
  __syncthreads();
  const int d = threadIdx.x;
  float a0 = 0.f, a1 = 0.f, a2 = 0.f;
#pragma unroll
  for (int k = 0; k < TOPK; ++k) {
    float v = sval[k];
    a0 = fmaf(v, Wd[(size_t)d * DS + sidx[k]], a0);
    a1 = fmaf(v, Wd[(size_t)(d + 256) * DS + sidx[k]], a1);
    a2 = fmaf(v, Wd[(size_t)(d + 512) * DS + sidx[k]], a2);
  }
  orow[d] = a0;
  orow[d + 256] = a1;
  orow[d + 512] = a2;
}

extern "C" void kernel_launch(void* const* d_in, const int* in_sizes, int n_in,
                              void* d_out, int out_size, void* d_ws, size_t ws_size,
                              hipStream_t stream) {
  const float* A    = (const float*)d_in[0];  // mlp_input [B][DM]
  const float* Wenc = (const float*)d_in[1];  // [DS][DM]
  const float* benc = (const float*)d_in[2];  // [DS]
  const float* Wdec = (const float*)d_in[3];  // [DM][DS]

  float* out0    = (float*)d_out;                  // [B][DM]
  float* latents = out0 + (size_t)B_SZ * DM;       // [B][DS]

  const size_t wdt_bytes = (size_t)DS * DM * sizeof(float);
  const bool big_ws = ws_size >= wdt_bytes;
  float* WdT = (float*)d_ws;

  // 1. encode GEMM: pre-activations staged in the latents output region
  k_gemm<<<dim3(DS / 64, B_SZ / 64), 256, 0, stream>>>(A, Wenc, benc, latents);

  // 2. per-row top-32 (fp64-refined); (val,idx) lists staged in out0 rows
  k_topk<<<B_SZ, 256, 0, stream>>>(latents, A, Wenc, benc, out0);

  // 3. zero latents, scatter survivors
  hipMemsetAsync(latents, 0, (size_t)B_SZ * DS * sizeof(float), stream);
  k_scatter<<<(B_SZ * TOPK + 255) / 256, 256, 0, stream>>>(out0, latents);

  // 4. decode (overwrites out0 after loading its lists)
  if (big_ws) {
    k_transpose<<<dim3(DS / 32, DM / 32), dim3(32, 8), 0, stream>>>(Wdec, WdT);
    k_decode<<<B_SZ, 256, 0, stream>>>(WdT, out0);
  } else {
    k_decode_slow<<<B_SZ, 256, 0, stream>>>(Wdec, out0);
  }
}

// Round 2
// 805.512 us; speedup vs baseline: 3.2258x; 3.2258x over previous
//
#include <hip/hip_runtime.h>

#define B_SZ 4096
#define DM   768
#define DS   24576
#define TOPK 32
#define MAXC 256

typedef _Float16 half8 __attribute__((ext_vector_type(8)));
typedef float f32x4 __attribute__((ext_vector_type(4)));

#define BM 128
#define BN 128
#define BK 64
#define PITCH 72  // halves per LDS row: 64 + 8 pad (144B, 16B-aligned, 2-way read aliasing = free)

// ---------------- Kernel 1: pre = A @ Wenc^T + b  (fp16 MFMA screening GEMM) ----------------
__global__ __launch_bounds__(256, 2) void k_gemm16(const float* __restrict__ A,
                                                   const float* __restrict__ W,
                                                   const float* __restrict__ bias,
                                                   float* __restrict__ pre) {
  __shared__ _Float16 Asl[BM * PITCH];
  __shared__ _Float16 Bsl[BM * PITCH];

  const int tid = threadIdx.x;
  const int n0 = blockIdx.x * BN;
  const int m0 = blockIdx.y * BM;
  const int lane = tid & 63;
  const int wid = tid >> 6;
  const int wm = (wid >> 1) * 64;
  const int wn = (wid & 1) * 64;

  f32x4 acc[4][4] = {{{0.f, 0.f, 0.f, 0.f}}};

  // staging registers: each thread owns 4 chunks of 8 consecutive K-floats per matrix
  float4 avv[4][2], bvv[4][2];

  auto issue_loads = [&](int kt) {
#pragma unroll
    for (int i = 0; i < 4; ++i) {
      const int c = tid + i * 256;       // chunk id 0..1023
      const int r = c >> 3;              // tile row 0..127
      const int kc = (c & 7) * 8;        // k offset within BK
      const float* pa = A + (size_t)(m0 + r) * DM + kt + kc;
      avv[i][0] = *reinterpret_cast<const float4*>(pa);
      avv[i][1] = *reinterpret_cast<const float4*>(pa + 4);
      const float* pb = W + (size_t)(n0 + r) * DM + kt + kc;
      bvv[i][0] = *reinterpret_cast<const float4*>(pb);
      bvv[i][1] = *reinterpret_cast<const float4*>(pb + 4);
    }
  };

  auto write_lds = [&]() {
#pragma unroll
    for (int i = 0; i < 4; ++i) {
      const int c = tid + i * 256;
      const int r = c >> 3;
      const int kc = (c & 7) * 8;
      float ta[8], tb[8];
      *reinterpret_cast<float4*>(ta) = avv[i][0];
      *reinterpret_cast<float4*>(ta + 4) = avv[i][1];
      *reinterpret_cast<float4*>(tb) = bvv[i][0];
      *reinterpret_cast<float4*>(tb + 4) = bvv[i][1];
      half8 ha, hb;
#pragma unroll
      for (int j = 0; j < 8; ++j) {
        ha[j] = (_Float16)ta[j];
        hb[j] = (_Float16)tb[j];
      }
      *reinterpret_cast<half8*>(&Asl[r * PITCH + kc]) = ha;
      *reinterpret_cast<half8*>(&Bsl[r * PITCH + kc]) = hb;
    }
  };

  auto compute = [&]() {
#pragma unroll
    for (int ks = 0; ks < 2; ++ks) {
      half8 af[4], bf[4];
#pragma unroll
      for (int mi = 0; mi < 4; ++mi)
        af[mi] = *reinterpret_cast<half8*>(
            &Asl[(wm + mi * 16 + (lane & 15)) * PITCH + ks * 32 + (lane >> 4) * 8]);
#pragma unroll
      for (int ni = 0; ni < 4; ++ni)
        bf[ni] = *reinterpret_cast<half8*>(
            &Bsl[(wn + ni * 16 + (lane & 15)) * PITCH + ks * 32 + (lane >> 4) * 8]);
#pragma unroll
      for (int mi = 0; mi < 4; ++mi)
#pragma unroll
        for (int ni = 0; ni < 4; ++ni)
          acc[mi][ni] = __builtin_amdgcn_mfma_f32_16x16x32_f16(af[mi], bf[ni], acc[mi][ni], 0, 0, 0);
    }
  };

  issue_loads(0);
  write_lds();
  __syncthreads();
#pragma unroll 1
  for (int kt = BK; kt < DM; kt += BK) {
    issue_loads(kt);   // prefetch next tile into registers (in flight during compute)
    compute();
    __syncthreads();   // everyone done reading LDS
    write_lds();       // waits on this thread's global loads, converts, writes
    __syncthreads();
  }
  compute();

  // epilogue: C[m][n] with col = lane&15, row = (lane>>4)*4 + reg  (m89-verified layout)
  const int cn = n0 + wn + (lane & 15);
#pragma unroll
  for (int ni = 0; ni < 4; ++ni) {
    const float bvs = bias[cn + ni * 16];
#pragma unroll
    for (int mi = 0; mi < 4; ++mi) {
      const int rm = m0 + wm + mi * 16 + (lane >> 4) * 4;
#pragma unroll
      for (int r = 0; r < 4; ++r)
        pre[(size_t)(rm + r) * DS + cn + ni * 16] = acc[mi][ni][r] + bvs;
    }
  }
}

// ---------------- Kernel 2: per-row top-32 with fp64 boundary refinement ----------------
// Writes lists into out0 row b: floats [0..31] = vals, ints (bitcast) [32..63] = idxs.
__global__ __launch_bounds__(256) void k_topk(const float* __restrict__ pre,
                                              const float* __restrict__ A,
                                              const float* __restrict__ W,
                                              const float* __restrict__ bias,
                                              float* __restrict__ out0) {
  const int b = blockIdx.x;
  const int tid = threadIdx.x;
  __shared__ int hist[1024];
  __shared__ int chunk[64];
  __shared__ float sBinLo;
  __shared__ int cnt;
  __shared__ int cidx[MAXC];
  __shared__ double cval[MAXC];

  const float* row = pre + (size_t)b * DS;

  for (int i = tid; i < 1024; i += 256) hist[i] = 0;
  if (tid == 0) cnt = 0;
  __syncthreads();

  // histogram of screened pre-activations, bins of width 1/32 over [-16,16)
  for (int i = tid; i < DS / 4; i += 256) {
    float4 v4 = reinterpret_cast<const float4*>(row)[i];
    const float vs[4] = {v4.x, v4.y, v4.z, v4.w};
#pragma unroll
    for (int c = 0; c < 4; ++c) {
      int bin = (int)((vs[c] + 16.f) * 32.f);
      bin = bin < 0 ? 0 : (bin > 1023 ? 1023 : bin);
      atomicAdd(&hist[bin], 1);
    }
  }
  __syncthreads();

  if (tid < 64) {
    int s = 0;
    for (int x = 0; x < 16; ++x) s += hist[tid * 16 + x];
    chunk[tid] = s;
  }
  __syncthreads();

  if (tid == 0) {
    int cum = 0, tb = 0;
    for (int c = 63; c >= 0; --c) {
      if (cum + chunk[c] >= TOPK) {
        int cc = cum;
        tb = c * 16;
        for (int x = 15; x >= 0; --x) {
          int bn = c * 16 + x;
          if (cc + hist[bn] >= TOPK) { tb = bn; break; }
          cc += hist[bn];
        }
        break;
      }
      cum += chunk[c];
    }
    int lb = tb - 2;  // two bins of margin (0.0625) for fp16-screening noise (~12 sigma)
    if (lb < 0) lb = 0;
    sBinLo = -16.f + (float)lb * (1.f / 32.f);
  }
  __syncthreads();

  const float binLo = sBinLo;
  for (int i = tid; i < DS / 4; i += 256) {
    float4 v4 = reinterpret_cast<const float4*>(row)[i];
    const float vs[4] = {v4.x, v4.y, v4.z, v4.w};
#pragma unroll
    for (int c = 0; c < 4; ++c) {
      if (vs[c] >= binLo) {
        int p = atomicAdd(&cnt, 1);
        if (p < MAXC) cidx[p] = i * 4 + c;
      }
    }
  }
  __syncthreads();
  const int n = cnt < MAXC ? cnt : MAXC;

  // fp64 recompute of each candidate's dot product (one wave per candidate, round-robin)
  const float* Ar = A + (size_t)b * DM;
  const int w = tid >> 6, lane = tid & 63;
  for (int c = w; c < n; c += 4) {
    const float* Wr = W + (size_t)cidx[c] * DM;
    double s = 0.0;
    for (int d = lane; d < DM; d += 64) s += (double)Ar[d] * (double)Wr[d];
#pragma unroll
    for (int off = 32; off > 0; off >>= 1) s += __shfl_down(s, off);
    if (lane == 0) cval[c] = s + (double)bias[cidx[c]];
  }
  __syncthreads();

  // exact rank (value desc, tie -> lower index), matching jax.lax.top_k
  float* orow = out0 + (size_t)b * DM;
  if (tid < n) {
    double dv = cval[tid];
    int di = cidx[tid];
    int r = 0;
    for (int j = 0; j < n; ++j) {
      double o = cval[j];
      if (o > dv || (o == dv && cidx[j] < di)) ++r;
    }
    if (r < TOPK) {
      orow[r] = (float)dv;
      reinterpret_cast<int*>(orow)[TOPK + r] = di;
    }
  }
}

// ---------------- Kernel 3: scatter top-k values into zeroed latents ----------------
__global__ void k_scatter(const float* __restrict__ out0, float* __restrict__ latents) {
  int t = blockIdx.x * 256 + threadIdx.x;
  if (t < B_SZ * TOPK) {
    int b = t >> 5;
    int k = t & 31;
    const float* orow = out0 + (size_t)b * DM;
    int idx = reinterpret_cast<const int*>(orow)[TOPK + k];
    latents[(size_t)b * DS + idx] = orow[k];
  }
}

// ---------------- Kernel 4a: transpose W_dec [DM][DS] -> WdT [DS][DM] ----------------
__global__ void k_transpose(const float* __restrict__ in, float* __restrict__ out) {
  __shared__ float t[32][33];
  int sx = blockIdx.x * 32 + threadIdx.x;
  int d0 = blockIdx.y * 32;
#pragma unroll
  for (int j = 0; j < 32; j += 8)
    t[threadIdx.y + j][threadIdx.x] = in[(size_t)(d0 + threadIdx.y + j) * DS + sx];
  __syncthreads();
  int dx = d0 + threadIdx.x;
  int s0 = blockIdx.x * 32;
#pragma unroll
  for (int j = 0; j < 32; j += 8)
    out[(size_t)(s0 + threadIdx.y + j) * DM + dx] = t[threadIdx.x][threadIdx.y + j];
}

// ---------------- Kernel 4b: decode with transposed W_dec (coalesced) ----------------
__global__ __launch_bounds__(256) void k_decode(const float* __restrict__ WdT,
                                                float* __restrict__ out0) {
  const int b = blockIdx.x;
  __shared__ int sidx[TOPK];
  __shared__ float sval[TOPK];
  float* orow = out0 + (size_t)b * DM;
  if (threadIdx.x < TOPK) {
    sval[threadIdx.x] = orow[threadIdx.x];
    sidx[threadIdx.x] = reinterpret_cast<const int*>(orow)[TOPK + threadIdx.x];
  }
  __syncthreads();
  const int d = threadIdx.x;
  float a0 = 0.f, a1 = 0.f, a2 = 0.f;
#pragma unroll
  for (int k = 0; k < TOPK; ++k) {
    const float* wr = WdT + (size_t)sidx[k] * DM;
    float v = sval[k];
    a0 = fmaf(v, wr[d], a0);
    a1 = fmaf(v, wr[d + 256], a1);
    a2 = fmaf(v, wr[d + 512], a2);
  }
  orow[d] = a0;
  orow[d + 256] = a1;
  orow[d + 512] = a2;
}

// ---------------- Kernel 4b': decode fallback without transpose (strided) ----------------
__global__ __launch_bounds__(256) void k_decode_slow(const float* __restrict__ Wd,
                                                     float* __restrict__ out0) {
  const int b = blockIdx.x;
  __shared__ int sidx[TOPK];
  __shared__ float sval[TOPK];
  float* orow = out0 + (size_t)b * DM;
  if (threadIdx.x < TOPK) {
    sval[threadIdx.x] = orow[threadIdx.x];
    sidx[threadIdx.x] = reinterpret_cast<const int*>(orow)[TOPK + threadIdx.x];
  }
  __syncthreads();
  const int d = threadIdx.x;
  float a0 = 0.f, a1 = 0.f, a2 = 0.f;
#pragma unroll
  for (int k = 0; k < TOPK; ++k) {
    float v = sval[k];
    a0 = fmaf(v, Wd[(size_t)d * DS + sidx[k]], a0);
    a1 = fmaf(v, Wd[(size_t)(d + 256) * DS + sidx[k]], a1);
    a2 = fmaf(v, Wd[(size_t)(d + 512) * DS + sidx[k]], a2);
  }
  orow[d] = a0;
  orow[d + 256] = a1;
  orow[d + 512] = a2;
}

extern "C" void kernel_launch(void* const* d_in, const int* in_sizes, int n_in,
                              void* d_out, int out_size, void* d_ws, size_t ws_size,
                              hipStream_t stream) {
  const float* A    = (const float*)d_in[0];  // mlp_input [B][DM]
  const float* Wenc = (const float*)d_in[1];  // [DS][DM]
  const float* benc = (const float*)d_in[2];  // [DS]
  const float* Wdec = (const float*)d_in[3];  // [DM][DS]

  float* out0    = (float*)d_out;                  // [B][DM]
  float* latents = out0 + (size_t)B_SZ * DM;       // [B][DS]

  const size_t wdt_bytes = (size_t)DS * DM * sizeof(float);
  const bool big_ws = ws_size >= wdt_bytes;
  float* WdT = (float*)d_ws;

  // 1. encode screening GEMM (fp16 MFMA): pre-activations staged in latents region
  k_gemm16<<<dim3(DS / BN, B_SZ / BM), 256, 0, stream>>>(A, Wenc, benc, latents);

  // 2. per-row top-32 (fp64-refined); (val,idx) lists staged in out0 rows
  k_topk<<<B_SZ, 256, 0, stream>>>(latents, A, Wenc, benc, out0);

  // 3. zero latents, scatter survivors
  hipMemsetAsync(latents, 0, (size_t)B_SZ * DS * sizeof(float), stream);
  k_scatter<<<(B_SZ * TOPK + 255) / 256, 256, 0, stream>>>(out0, latents);

  // 4. decode (overwrites out0 after loading its lists)
  if (big_ws) {
    k_transpose<<<dim3(DS / 32, DM / 32), dim3(32, 8), 0, stream>>>(Wdec, WdT);
    k_decode<<<B_SZ, 256, 0, stream>>>(WdT, out0);
  } else {
    k_decode_slow<<<B_SZ, 256, 0, stream>>>(Wdec, out0);
  }
}

// Round 3
// 623.713 us; speedup vs baseline: 4.1660x; 1.2915x over previous
//
#include <hip/hip_runtime.h>

#define B_SZ 4096
#define DM   768
#define DS   24576
#define TOPK 32
#define MAXC 256
#define NKT  (DM / 64)  // 12 K-steps of 64

typedef _Float16 half8 __attribute__((ext_vector_type(8)));
typedef float f32x4 __attribute__((ext_vector_type(4)));

typedef const __attribute__((address_space(1))) void* gas_ptr;
typedef __attribute__((address_space(3))) void* las_ptr;

// ---------------- Kernel 0: fp32 [R][DM] -> fp16, K-step-local XOR-swizzled ----------------
// Element (row, kt*64 + kloc) stored at (row, kt*64 + (kloc ^ ((row&7)<<3))).
// 8-half blocks permute wholesale: dest block j' = j ^ (row&7). This pre-applies the T2
// LDS swizzle so the GEMM can global_load_lds linearly and ds_read with the same XOR.
__global__ void k_conv(const float* __restrict__ src, _Float16* __restrict__ dst, int R) {
  int t = blockIdx.x * 256 + threadIdx.x;  // one 8-half block per thread
  if (t >= R * (DM / 8)) return;
  int row = t / (DM / 8);
  int g = t % (DM / 8);
  int kt = g >> 3;
  int j = g & 7;
  int jd = j ^ (row & 7);
  const float* s = src + (size_t)row * DM + kt * 64 + j * 8;
  float4 a = *reinterpret_cast<const float4*>(s);
  float4 b = *reinterpret_cast<const float4*>(s + 4);
  half8 h;
  h[0] = (_Float16)a.x; h[1] = (_Float16)a.y; h[2] = (_Float16)a.z; h[3] = (_Float16)a.w;
  h[4] = (_Float16)b.x; h[5] = (_Float16)b.y; h[6] = (_Float16)b.z; h[7] = (_Float16)b.w;
  *reinterpret_cast<half8*>(dst + (size_t)row * DM + kt * 64 + jd * 8) = h;
}

// ---------------- Kernel 1: pre16 = fp16(A @ Wenc^T + b), m97-structure MFMA GEMM ----------------
__global__ __launch_bounds__(256, 2) void k_gemm16(const _Float16* __restrict__ A16,
                                                   const _Float16* __restrict__ W16,
                                                   const float* __restrict__ bias,
                                                   _Float16* __restrict__ pre) {
  __shared__ _Float16 Asl[128 * 64];  // [row][64 halves], 128B pitch, swizzled content
  __shared__ _Float16 Bsl[128 * 64];

  // XCD-aware swizzle: 6144 blocks, 8 XCDs, 768 contiguous per XCD (6144 % 8 == 0)
  const int bid = blockIdx.x;
  const int sbid = (bid & 7) * 768 + (bid >> 3);
  const int m0 = (sbid / 192) * 128;
  const int n0 = (sbid % 192) * 128;

  const int tid = threadIdx.x;
  const int lane = tid & 63;
  const int wid = tid >> 6;
  const int wm = (wid >> 1) * 64;
  const int wn = (wid & 1) * 64;

  f32x4 acc[4][4];
#pragma unroll
  for (int mi = 0; mi < 4; ++mi)
#pragma unroll
    for (int ni = 0; ni < 4; ++ni) acc[mi][ni] = (f32x4){0.f, 0.f, 0.f, 0.f};

  auto stage = [&](int kt) {
#pragma unroll
    for (int i = 0; i < 4; ++i) {
      const int c = tid + i * 256;   // chunk 0..1023: row = c>>3, 16B-seg = c&7
      const int row = c >> 3;
      const int seg = c & 7;
      const _Float16* ga = A16 + (size_t)(m0 + row) * DM + kt * 64 + seg * 8;
      const _Float16* gb = W16 + (size_t)(n0 + row) * DM + kt * 64 + seg * 8;
      // wave-uniform LDS base; HW adds lane*16
      _Float16* la = &Asl[(i * 256 + wid * 64) * 8];
      _Float16* lb = &Bsl[(i * 256 + wid * 64) * 8];
      __builtin_amdgcn_global_load_lds((gas_ptr)ga, (las_ptr)la, 16, 0, 0);
      __builtin_amdgcn_global_load_lds((gas_ptr)gb, (las_ptr)lb, 16, 0, 0);
    }
  };

  auto compute = [&]() {
#pragma unroll
    for (int ks = 0; ks < 2; ++ks) {
      half8 af[4], bf[4];
#pragma unroll
      for (int mi = 0; mi < 4; ++mi) {
        const int r = wm + mi * 16 + (lane & 15);
        const int byteoff = ((ks * 64 + (lane >> 4) * 16) ^ ((r & 7) << 4));
        af[mi] = *reinterpret_cast<const half8*>(reinterpret_cast<const char*>(Asl) + r * 128 + byteoff);
      }
#pragma unroll
      for (int ni = 0; ni < 4; ++ni) {
        const int r = wn + ni * 16 + (lane & 15);
        const int byteoff = ((ks * 64 + (lane >> 4) * 16) ^ ((r & 7) << 4));
        bf[ni] = *reinterpret_cast<const half8*>(reinterpret_cast<const char*>(Bsl) + r * 128 + byteoff);
      }
#pragma unroll
      for (int mi = 0; mi < 4; ++mi)
#pragma unroll
        for (int ni = 0; ni < 4; ++ni)
          acc[mi][ni] = __builtin_amdgcn_mfma_f32_16x16x32_f16(af[mi], bf[ni], acc[mi][ni], 0, 0, 0);
    }
  };

  stage(0);
#pragma unroll 1
  for (int kt = 0;; ++kt) {
    __syncthreads();  // staged tile visible (compiler drains vmcnt before s_barrier)
    compute();
    if (kt == NKT - 1) break;
    __syncthreads();  // all waves done reading LDS
    stage(kt + 1);
  }

  // epilogue: C layout col = lane&15, row = (lane>>4)*4 + r (m89-verified); write fp16
  const int cn = n0 + wn + (lane & 15);
  const int rb = m0 + wm + (lane >> 4) * 4;
#pragma unroll
  for (int ni = 0; ni < 4; ++ni) {
    const float bv = bias[cn + ni * 16];
#pragma unroll
    for (int mi = 0; mi < 4; ++mi)
#pragma unroll
      for (int r = 0; r < 4; ++r)
        pre[(size_t)(rb + mi * 16 + r) * DS + cn + ni * 16] = (_Float16)(acc[mi][ni][r] + bv);
  }
}

// ---------------- Kernel 2: single-pass per-row top-32 with fp64 boundary refinement ----------------
// Per-thread register top-8 over 96 strided values -> 2048-candidate histogram -> threshold
// (-2 bins = 0.0625 margin >> fp16 screening noise) -> fp64 refine -> exact rank.
// Lists into out0 row b: floats [0..31] = vals, ints (bitcast) [32..63] = idxs.
__global__ __launch_bounds__(256) void k_topk(const _Float16* __restrict__ pre,
                                              const float* __restrict__ A,
                                              const float* __restrict__ W,
                                              const float* __restrict__ bias,
                                              float* __restrict__ out0) {
  const int b = blockIdx.x;
  const int tid = threadIdx.x;
  __shared__ int hist[1024];
  __shared__ int chunkS[64];
  __shared__ float sBinLo;
  __shared__ int cnt;
  __shared__ int cidx[MAXC];
  __shared__ double cval[MAXC];

  const _Float16* row = pre + (size_t)b * DS;

  float tv[8];
  int ti[8];
#pragma unroll
  for (int j = 0; j < 8; ++j) { tv[j] = -1e30f; ti[j] = 0; }
  float tmin = -1e30f;
  int tslot = 0;

#pragma unroll 1
  for (int i = 0; i < 12; ++i) {
    const int ch = tid + i * 256;
    half8 h = *reinterpret_cast<const half8*>(row + ch * 8);
#pragma unroll
    for (int j = 0; j < 8; ++j) {
      float v = (float)h[j];
      if (v > tmin) {
        tv[tslot] = v;
        ti[tslot] = ch * 8 + j;
        tmin = tv[0]; tslot = 0;
#pragma unroll
        for (int q = 1; q < 8; ++q)
          if (tv[q] < tmin) { tmin = tv[q]; tslot = q; }
      }
    }
  }

  for (int i = tid; i < 1024; i += 256) hist[i] = 0;
  if (tid == 0) cnt = 0;
  __syncthreads();

#pragma unroll
  for (int j = 0; j < 8; ++j) {
    int bin = (int)((tv[j] + 16.f) * 32.f);
    bin = bin < 0 ? 0 : (bin > 1023 ? 1023 : bin);
    atomicAdd(&hist[bin], 1);
  }
  __syncthreads();

  if (tid < 64) {
    int s = 0;
    for (int x = 0; x < 16; ++x) s += hist[tid * 16 + x];
    chunkS[tid] = s;
  }
  __syncthreads();

  if (tid == 0) {
    int cum = 0, tb = 0;
    for (int c = 63; c >= 0; --c) {
      if (cum + chunkS[c] >= TOPK) {
        int cc = cum;
        tb = c * 16;
        for (int x = 15; x >= 0; --x) {
          int bn = c * 16 + x;
          if (cc + hist[bn] >= TOPK) { tb = bn; break; }
          cc += hist[bn];
        }
        break;
      }
      cum += chunkS[c];
    }
    int lb = tb - 2;  // 0.0625 margin for fp16 screening noise
    if (lb < 0) lb = 0;
    sBinLo = -16.f + (float)lb * (1.f / 32.f);
  }
  __syncthreads();

  const float binLo = sBinLo;
#pragma unroll
  for (int j = 0; j < 8; ++j) {
    if (tv[j] >= binLo) {
      int p = atomicAdd(&cnt, 1);
      if (p < MAXC) cidx[p] = ti[j];
    }
  }
  __syncthreads();
  const int n = cnt < MAXC ? cnt : MAXC;

  // fp64 recompute of each candidate (one wave per candidate, round-robin)
  const float* Ar = A + (size_t)b * DM;
  const int w = tid >> 6, lane = tid & 63;
  for (int c = w; c < n; c += 4) {
    const float* Wr = W + (size_t)cidx[c] * DM;
    double s = 0.0;
    for (int d = lane; d < DM; d += 64) s += (double)Ar[d] * (double)Wr[d];
#pragma unroll
    for (int off = 32; off > 0; off >>= 1) s += __shfl_down(s, off);
    if (lane == 0) cval[c] = s + (double)bias[cidx[c]];
  }
  __syncthreads();

  // exact rank (value desc, tie -> lower index), matching jax.lax.top_k
  float* orow = out0 + (size_t)b * DM;
  if (tid < n) {
    double dv = cval[tid];
    int di = cidx[tid];
    int r = 0;
    for (int j = 0; j < n; ++j) {
      double o = cval[j];
      if (o > dv || (o == dv && cidx[j] < di)) ++r;
    }
    if (r < TOPK) {
      orow[r] = (float)dv;
      reinterpret_cast<int*>(orow)[TOPK + r] = di;
    }
  }
}

// ---------------- Kernel 3: scatter top-k values into zeroed latents ----------------
__global__ void k_scatter(const float* __restrict__ out0, float* __restrict__ latents) {
  int t = blockIdx.x * 256 + threadIdx.x;
  if (t < B_SZ * TOPK) {
    int b = t >> 5;
    int k = t & 31;
    const float* orow = out0 + (size_t)b * DM;
    int idx = reinterpret_cast<const int*>(orow)[TOPK + k];
    latents[(size_t)b * DS + idx] = orow[k];
  }
}

// ---------------- Kernel 4a: transpose W_dec [DM][DS] -> WdT [DS][DM] ----------------
__global__ void k_transpose(const float* __restrict__ in, float* __restrict__ out) {
  __shared__ float t[32][33];
  int sx = blockIdx.x * 32 + threadIdx.x;
  int d0 = blockIdx.y * 32;
#pragma unroll
  for (int j = 0; j < 32; j += 8)
    t[threadIdx.y + j][threadIdx.x] = in[(size_t)(d0 + threadIdx.y + j) * DS + sx];
  __syncthreads();
  int dx = d0 + threadIdx.x;
  int s0 = blockIdx.x * 32;
#pragma unroll
  for (int j = 0; j < 32; j += 8)
    out[(size_t)(s0 + threadIdx.y + j) * DM + dx] = t[threadIdx.x][threadIdx.y + j];
}

// ---------------- Kernel 4b: decode with transposed W_dec (coalesced) ----------------
__global__ __launch_bounds__(256) void k_decode(const float* __restrict__ WdT,
                                                float* __restrict__ out0) {
  const int b = blockIdx.x;
  __shared__ int sidx[TOPK];
  __shared__ float sval[TOPK];
  float* orow = out0 + (size_t)b * DM;
  if (threadIdx.x < TOPK) {
    sval[threadIdx.x] = orow[threadIdx.x];
    sidx[threadIdx.x] = reinterpret_cast<const int*>(orow)[TOPK + threadIdx.x];
  }
  __syncthreads();
  const int d = threadIdx.x;
  float a0 = 0.f, a1 = 0.f, a2 = 0.f;
#pragma unroll
  for (int k = 0; k < TOPK; ++k) {
    const float* wr = WdT + (size_t)sidx[k] * DM;
    float v = sval[k];
    a0 = fmaf(v, wr[d], a0);
    a1 = fmaf(v, wr[d + 256], a1);
    a2 = fmaf(v, wr[d + 512], a2);
  }
  orow[d] = a0;
  orow[d + 256] = a1;
  orow[d + 512] = a2;
}

// ---------------- Kernel 4b': decode fallback without transpose (strided) ----------------
__global__ __launch_bounds__(256) void k_decode_slow(const float* __restrict__ Wd,
                                                     float* __restrict__ out0) {
  const int b = blockIdx.x;
  __shared__ int sidx[TOPK];
  __shared__ float sval[TOPK];
  float* orow = out0 + (size_t)b * DM;
  if (threadIdx.x < TOPK) {
    sval[threadIdx.x] = orow[threadIdx.x];
    sidx[threadIdx.x] = reinterpret_cast<const int*>(orow)[TOPK + threadIdx.x];
  }
  __syncthreads();
  const int d = threadIdx.x;
  float a0 = 0.f, a1 = 0.f, a2 = 0.f;
#pragma unroll
  for (int k = 0; k < TOPK; ++k) {
    float v = sval[k];
    a0 = fmaf(v, Wd[(size_t)d * DS + sidx[k]], a0);
    a1 = fmaf(v, Wd[(size_t)(d + 256) * DS + sidx[k]], a1);
    a2 = fmaf(v, Wd[(size_t)(d + 512) * DS + sidx[k]], a2);
  }
  orow[d] = a0;
  orow[d + 256] = a1;
  orow[d + 512] = a2;
}

extern "C" void kernel_launch(void* const* d_in, const int* in_sizes, int n_in,
                              void* d_out, int out_size, void* d_ws, size_t ws_size,
                              hipStream_t stream) {
  const float* A    = (const float*)d_in[0];  // mlp_input [B][DM]
  const float* Wenc = (const float*)d_in[1];  // [DS][DM]
  const float* benc = (const float*)d_in[2];  // [DS]
  const float* Wdec = (const float*)d_in[3];  // [DM][DS]

  float* out0    = (float*)d_out;             // [B][DM]
  float* latents = out0 + (size_t)B_SZ * DM;  // [B][DS], 402.7 MB

  // scratch carved from the latents output region (dead until memset):
  //   pre16  [B][DS]  fp16  201.3 MB
  //   A16    [B][DM]  fp16    6.3 MB (swizzled)
  //   W16    [DS][DM] fp16   37.7 MB (swizzled)
  _Float16* pre16 = (_Float16*)latents;
  _Float16* A16   = pre16 + (size_t)B_SZ * DS;
  _Float16* W16   = A16 + (size_t)B_SZ * DM;

  const size_t wdt_bytes = (size_t)DS * DM * sizeof(float);
  const bool big_ws = ws_size >= wdt_bytes;
  float* WdT = (float*)d_ws;

  // 0. convert inputs to swizzled fp16
  k_conv<<<(B_SZ * (DM / 8) + 255) / 256, 256, 0, stream>>>(A, A16, B_SZ);
  k_conv<<<(DS * (DM / 8) + 255) / 256, 256, 0, stream>>>(Wenc, W16, DS);

  // 1. encode screening GEMM (fp16 MFMA, global_load_lds staging, XCD swizzle)
  k_gemm16<<<(DS / 128) * (B_SZ / 128), 256, 0, stream>>>(A16, W16, benc, pre16);

  // 2. per-row top-32 (single pass + fp64 refine); lists staged in out0 rows
  k_topk<<<B_SZ, 256, 0, stream>>>(pre16, A, Wenc, benc, out0);

  // 3. zero latents (kills pre16/A16/W16 — all consumed), scatter survivors
  hipMemsetAsync(latents, 0, (size_t)B_SZ * DS * sizeof(float), stream);
  k_scatter<<<(B_SZ * TOPK + 255) / 256, 256, 0, stream>>>(out0, latents);

  // 4. decode (overwrites out0 after loading its lists)
  if (big_ws) {
    k_transpose<<<dim3(DS / 32, DM / 32), dim3(32, 8), 0, stream>>>(Wdec, WdT);
    k_decode<<<B_SZ, 256, 0, stream>>>(WdT, out0);
  } else {
    k_decode_slow<<<B_SZ, 256, 0, stream>>>(Wdec, out0);
  }
}